// Round 2
// baseline (320.516 us; speedup 1.0000x reference)
//
#include <hip/hip_runtime.h>
#include <hip/hip_bf16.h>

typedef unsigned short u16;
typedef __attribute__((ext_vector_type(8))) __bf16 v8bf;
typedef __attribute__((ext_vector_type(4))) float v4f;

#define DEVINL __device__ __forceinline__

DEVINL u16 f2bf(float f) {
  union { float f; unsigned u; } v; v.f = f;
  unsigned u = v.u;
  return (u16)((u + 0x7FFFu + ((u >> 16) & 1u)) >> 16);  // RNE
}
DEVINL float bf2f(u16 b) {
  union { unsigned u; float f; } v; v.u = ((unsigned)b) << 16;
  return v.f;
}

// async global->LDS, 16B per lane; dest is wave-uniform base + lane*16
DEVINL void async16(const void* g, void* l) {
  __builtin_amdgcn_global_load_lds(
      (__attribute__((address_space(1))) void*)(g),
      (__attribute__((address_space(3))) void*)(l), 16, 0, 0);
}

// ---------------- elementwise fp32 -> bf16 ----------------
__global__ __launch_bounds__(256) void k_f2b(const float* __restrict__ src,
                                             u16* __restrict__ dst, int n) {
  int i = (blockIdx.x * 256 + threadIdx.x) * 4;
  if (i + 3 < n) {
    float4 v = *(const float4*)(src + i);
    unsigned lo = (unsigned)f2bf(v.x) | ((unsigned)f2bf(v.y) << 16);
    unsigned hi = (unsigned)f2bf(v.z) | ((unsigned)f2bf(v.w) << 16);
    uint2 o; o.x = lo; o.y = hi;
    *(uint2*)(dst + i) = o;
  }
}

// ---------------- tiled transpose + convert: src fp32 [R][C] -> dst bf16 [C][R] ----------------
__global__ __launch_bounds__(256) void k_transpose_f2b(
    const float* __restrict__ src, u16* __restrict__ dst,
    int R, int C, long srcBatch, long dstBatch) {
  __shared__ float tile[32][33];
  int z = blockIdx.z;
  src += (long)z * srcBatch;
  dst += (long)z * dstBatch;
  int r0 = blockIdx.y * 32, c0 = blockIdx.x * 32;
  int tx = threadIdx.x & 31, ty = threadIdx.x >> 5;  // ty 0..7
#pragma unroll
  for (int i = 0; i < 4; ++i) {
    int rr = ty + i * 8;
    tile[rr][tx] = src[(long)(r0 + rr) * C + c0 + tx];
  }
  __syncthreads();
#pragma unroll
  for (int i = 0; i < 4; ++i) {
    int rr = ty + i * 8;
    dst[(long)(c0 + rr) * R + r0 + tx] = f2bf(tile[tx][rr]);
  }
}

// ---------------- fused bias for the reduce GEMM ----------------
__global__ __launch_bounds__(256) void k_bias_fused(
    const u16* __restrict__ dw1t, const float* __restrict__ eb2,
    const float* __restrict__ db1, float* __restrict__ biasf) {
  int r = blockIdx.x;  // 0..511
  const u16* row = dw1t + (long)r * 12800;
  float s = 0.f;
  for (int i = threadIdx.x; i < 12800; i += 256) s += bf2f(row[i]) * eb2[i];
  __shared__ float red[256];
  red[threadIdx.x] = s;
  __syncthreads();
  for (int off = 128; off > 0; off >>= 1) {
    if (threadIdx.x < off) red[threadIdx.x] += red[threadIdx.x + off];
    __syncthreads();
  }
  if (threadIdx.x == 0) biasf[r] = red[0] + db1[r];
}

// ---------------- concat two length-n fp32 vectors ----------------
__global__ __launch_bounds__(256) void k_concat2(const float* __restrict__ a,
                                                 const float* __restrict__ b,
                                                 float* __restrict__ dst, int n) {
  int i = blockIdx.x * 256 + threadIdx.x;
  if (i < n) dst[i] = a[i];
  else if (i < 2 * n) dst[i] = b[i - n];
}

// ---------------- 128x128 MFMA GEMM (small problems) ----------------
__global__ __launch_bounds__(256) void k_gemm(
    const u16* __restrict__ A, int lda, long aBatch,
    const u16* __restrict__ B, int ldb, long bBatch,   // B is Bt: [N][K]
    void* __restrict__ Cp, int ldc, long cBatch,
    int K,
    const float* __restrict__ bias, long biasBatch,
    const float* __restrict__ rowscale, int flags) {
  __shared__ __align__(16) u16 As[2][128 * 32];
  __shared__ __align__(16) u16 Bs[2][128 * 32];
  const int tid = threadIdx.x;
  const int w = tid >> 6, l = tid & 63;
  const int z = blockIdx.z;
  const u16* Ab = A + (long)z * aBatch + (long)blockIdx.y * 128 * lda;
  const u16* Bb = B + (long)z * bBatch + (long)blockIdx.x * 128 * ldb;
  const int ldaB = lda * 2, ldbB = ldb * 2;
  const int wm = w >> 1, wn = w & 1;
  const int r = l & 15, kq = l >> 4;

  const int f0 = w * 1024 + l * 16;
  const int f1 = f0 + 4096;
  const int row0 = f0 >> 6, cb0 = f0 & 63;
  const int row1 = f1 >> 6, cb1 = f1 & 63;
  const int seg0 = w * 1024, seg1 = seg0 + 4096;

  v4f acc[4][4];
#pragma unroll
  for (int m = 0; m < 4; ++m)
#pragma unroll
    for (int n = 0; n < 4; ++n) acc[m][n] = v4f{0.f, 0.f, 0.f, 0.f};

  const char* gA = (const char*)Ab;
  const char* gB = (const char*)Bb;
  const int nkt = K / 32;

  async16(gA + (long)row0 * ldaB + cb0, (char*)As[0] + seg0);
  async16(gA + (long)row1 * ldaB + cb1, (char*)As[0] + seg1);
  async16(gB + (long)row0 * ldbB + cb0, (char*)Bs[0] + seg0);
  async16(gB + (long)row1 * ldbB + cb1, (char*)Bs[0] + seg1);
  __syncthreads();

  for (int kt = 0; kt < nkt; ++kt) {
    const int cur = kt & 1;
    if (kt + 1 < nkt) {
      const long ko = (long)(kt + 1) * 64;
      async16(gA + ko + (long)row0 * ldaB + cb0, (char*)As[cur ^ 1] + seg0);
      async16(gA + ko + (long)row1 * ldaB + cb1, (char*)As[cur ^ 1] + seg1);
      async16(gB + ko + (long)row0 * ldbB + cb0, (char*)Bs[cur ^ 1] + seg0);
      async16(gB + ko + (long)row1 * ldbB + cb1, (char*)Bs[cur ^ 1] + seg1);
    }
    v8bf af[4], bfr[4];
#pragma unroll
    for (int m = 0; m < 4; ++m)
      af[m] = *(const v8bf*)&As[cur][(wm * 64 + m * 16 + r) * 32 + kq * 8];
#pragma unroll
    for (int n = 0; n < 4; ++n)
      bfr[n] = *(const v8bf*)&Bs[cur][(wn * 64 + n * 16 + r) * 32 + kq * 8];
#pragma unroll
    for (int m = 0; m < 4; ++m)
#pragma unroll
      for (int n = 0; n < 4; ++n)
        acc[m][n] = __builtin_amdgcn_mfma_f32_16x16x32_bf16(af[m], bfr[n], acc[m][n], 0, 0, 0);
    __syncthreads();
  }

  const float* bz = bias ? (bias + (long)z * biasBatch) : nullptr;
  const long rowBase = (long)blockIdx.y * 128 + wm * 64 + kq * 4;
  const int colBase = blockIdx.x * 128 + wn * 64 + r;
  float* Cf = (float*)Cp + (long)z * cBatch;
  u16* Ch = (u16*)Cp + (long)z * cBatch;
#pragma unroll
  for (int m = 0; m < 4; ++m) {
#pragma unroll
    for (int n = 0; n < 4; ++n) {
      const int col = colBase + n * 16;
      const float bv = bz ? bz[col] : 0.f;
#pragma unroll
      for (int i = 0; i < 4; ++i) {
        const long row = rowBase + m * 16 + i;
        float v = acc[m][n][i] + bv;
        if (flags & 1) v = fmaxf(v, 0.f);
        if (rowscale) v *= rowscale[row];
        const long idx = row * ldc + col;
        if (flags & 2) Cf[idx] = v;
        else Ch[idx] = f2bf(v);
      }
    }
  }
}

// ======================= 256x256 8-phase MFMA GEMM =======================
// BM=BN=256, BK=64, 512 threads = 8 waves (2M x 4N), per-wave out 128x64.
// LDS 128 KiB: [buf][op][256*64] bf16, XOR-swizzled (colbyte ^= (row&7)<<4),
// staged via global_load_lds with pre-swizzled per-lane source addresses.
// Counted vmcnt(6) at phases 4/8; setprio around MFMA clusters.
// Requires: M%256==0, N%256==0, K%128==0, K>=256.

#define LDS_T(buf, op) (smem + ((buf) * 2 + (op)) * 16384)

#define READ_A(buf, mh) do {                                                   \
  const char* _t = (const char*)LDS_T(buf, 0);                                 \
  _Pragma("unroll") for (int m = 0; m < 4; ++m)                                \
    _Pragma("unroll") for (int kk = 0; kk < 2; ++kk)                           \
      a[m][kk] = *(const v8bf*)(_t +                                           \
        (wm * 128 + (mh) * 64 + m * 16 + r15) * 128 +                          \
        ((kk * 64 + kq * 16) ^ (swr << 4)));                                   \
} while (0)

#define READ_B(buf, nh, br) do {                                               \
  const char* _t = (const char*)LDS_T(buf, 1);                                 \
  _Pragma("unroll") for (int n = 0; n < 2; ++n)                                \
    _Pragma("unroll") for (int kk = 0; kk < 2; ++kk)                           \
      br[n][kk] = *(const v8bf*)(_t +                                          \
        (wn * 64 + (nh) * 32 + n * 16 + r15) * 128 +                           \
        ((kk * 64 + kq * 16) ^ (swr << 4)));                                   \
} while (0)

#define MMA(mh, nh, br) do {                                                   \
  _Pragma("unroll") for (int kk = 0; kk < 2; ++kk)                             \
    _Pragma("unroll") for (int m = 0; m < 4; ++m)                              \
      _Pragma("unroll") for (int n = 0; n < 2; ++n)                            \
        acc[(mh) * 4 + m][(nh) * 2 + n] =                                      \
          __builtin_amdgcn_mfma_f32_16x16x32_bf16(                             \
            a[m][kk], br[n][kk], acc[(mh) * 4 + m][(nh) * 2 + n], 0, 0, 0);    \
} while (0)

#define BAR() __builtin_amdgcn_s_barrier()
#define PRIO1() __builtin_amdgcn_s_setprio(1)
#define PRIO0() __builtin_amdgcn_s_setprio(0)
#define VM6() asm volatile("s_waitcnt vmcnt(6)" ::: "memory")
#define VM0() asm volatile("s_waitcnt vmcnt(0)" ::: "memory")

__global__ __launch_bounds__(512, 2) void k_gemm256(
    const u16* __restrict__ A, int lda, long aBatch,
    const u16* __restrict__ B, int ldb, long bBatch,   // B is Bt: [N][K]
    void* __restrict__ Cp, int ldc, long cBatch,
    int K,
    const float* __restrict__ bias,
    const float* __restrict__ rowscale, int flags) {
  __shared__ __align__(16) u16 smem[2 * 2 * 16384];  // 128 KiB

  const int tid = threadIdx.x;
  const int w = tid >> 6, l = tid & 63;
  const int wm = w >> 2, wn = w & 3;
  const int r15 = l & 15, kq = l >> 4, swr = l & 7;
  const int z = blockIdx.z;

  // staging constants: lane covers row (R0 + rl), swizzled col byte scol
  const int rl = l >> 3;
  const int scol = ((l & 7) ^ rl) << 4;

  const long ldaB = (long)lda * 2, ldbB = (long)ldb * 2;
  const char* gAs = (const char*)(A + (long)z * aBatch) +
                    ((long)blockIdx.y * 256 + rl) * ldaB + scol;
  const char* gBs = (const char*)(B + (long)z * bBatch) +
                    ((long)blockIdx.x * 256 + rl) * ldbB + scol;

  auto stA = [&](int buf, int R0, int kt) {
    async16(gAs + (long)R0 * ldaB + (long)kt * 128, (char*)LDS_T(buf, 0) + R0 * 128);
  };
  auto stB = [&](int buf, int R0, int kt) {
    async16(gBs + (long)R0 * ldbB + (long)kt * 128, (char*)LDS_T(buf, 1) + R0 * 128);
  };
  auto stAU0 = [&](int buf, int kt) { stA(buf, w * 8, kt);       stA(buf, 128 + w * 8, kt); };
  auto stAU1 = [&](int buf, int kt) { stA(buf, 64 + w * 8, kt);  stA(buf, 192 + w * 8, kt); };
  auto stBU0 = [&](int buf, int kt) { int R = (w >> 1) * 64 + (w & 1) * 16;      stB(buf, R, kt); stB(buf, R + 8, kt); };
  auto stBU1 = [&](int buf, int kt) { int R = (w >> 1) * 64 + (w & 1) * 16 + 32; stB(buf, R, kt); stB(buf, R + 8, kt); };

  v4f acc[8][4];
#pragma unroll
  for (int m = 0; m < 8; ++m)
#pragma unroll
    for (int n = 0; n < 4; ++n) acc[m][n] = v4f{0.f, 0.f, 0.f, 0.f};
  v8bf a[4][2], b0[2][2], b1[2][2];

  const int NT = K >> 6;        // K/64 tiles; NT even, >= 4
  const int NI = (NT >> 1) - 1; // full iterations before epilogue

  // prologue: tile0 -> buf0 (all 4 chunks), tile1 -> buf1 (3 of 4 chunks)
  stAU0(0, 0); stBU0(0, 0); stBU1(0, 0); stAU1(0, 0);
  stAU0(1, 1); stBU0(1, 1); stBU1(1, 1);
  VM6();  // buf0 fully landed (<=6 outstanding = buf1's 3 chunks)
  BAR();

  int kt0 = 0;
  for (int i = 0; i < NI; ++i, kt0 += 2) {
    // P1: q00 of buf0 (tile kt0); stage buf1.A-U1 <- kt0+1
    READ_A(0, 0); READ_B(0, 0, b0);
    stAU1(1, kt0 + 1);
    BAR(); PRIO1(); MMA(0, 0, b0); PRIO0(); BAR();
    // P2: q01; stage buf0.A-U0 <- kt0+2
    READ_B(0, 1, b1);
    stAU0(0, kt0 + 2);
    BAR(); PRIO1(); MMA(0, 1, b1); PRIO0(); BAR();
    // P3: q11; stage buf0.B-U0 <- kt0+2
    READ_A(0, 1);
    stBU0(0, kt0 + 2);
    BAR(); PRIO1(); MMA(1, 1, b1); PRIO0(); BAR();
    // P4: q10; stage buf0.B-U1 <- kt0+2; counted wait
    stBU1(0, kt0 + 2);
    BAR(); PRIO1(); MMA(1, 0, b0); PRIO0(); VM6(); BAR();
    // P5: q00 of buf1 (tile kt0+1); stage buf0.A-U1 <- kt0+2
    READ_A(1, 0); READ_B(1, 0, b0);
    stAU1(0, kt0 + 2);
    BAR(); PRIO1(); MMA(0, 0, b0); PRIO0(); BAR();
    // P6: q01; stage buf1.A-U0 <- kt0+3
    READ_B(1, 1, b1);
    stAU0(1, kt0 + 3);
    BAR(); PRIO1(); MMA(0, 1, b1); PRIO0(); BAR();
    // P7: q11; stage buf1.B-U0 <- kt0+3
    READ_A(1, 1);
    stBU0(1, kt0 + 3);
    BAR(); PRIO1(); MMA(1, 1, b1); PRIO0(); BAR();
    // P8: q10; stage buf1.B-U1 <- kt0+3; counted wait
    stBU1(1, kt0 + 3);
    BAR(); PRIO1(); MMA(1, 0, b0); PRIO0(); VM6(); BAR();
  }

  // epilogue iteration: tiles NT-2 (buf0), NT-1 (buf1); only P1 stages
  READ_A(0, 0); READ_B(0, 0, b0);
  stAU1(1, kt0 + 1);
  BAR(); PRIO1(); MMA(0, 0, b0); PRIO0(); BAR();
  READ_B(0, 1, b1);
  BAR(); PRIO1(); MMA(0, 1, b1); PRIO0(); BAR();
  READ_A(0, 1);
  BAR(); PRIO1(); MMA(1, 1, b1); PRIO0(); BAR();
  BAR(); PRIO1(); MMA(1, 0, b0); PRIO0(); VM0(); BAR();
  READ_A(1, 0); READ_B(1, 0, b0);
  BAR(); PRIO1(); MMA(0, 0, b0); PRIO0(); BAR();
  READ_B(1, 1, b1);
  BAR(); PRIO1(); MMA(0, 1, b1); PRIO0(); BAR();
  READ_A(1, 1);
  BAR(); PRIO1(); MMA(1, 1, b1); PRIO0(); BAR();
  PRIO1(); MMA(1, 0, b0); PRIO0();

  // epilogue: row = by*256 + wm*128 + mf*16 + kq*4 + j ; col = bx*256 + wn*64 + nf*16 + r15
  const long rowBase = (long)blockIdx.y * 256 + wm * 128 + kq * 4;
  const int colBase = blockIdx.x * 256 + wn * 64 + r15;
  float* Cf = (float*)Cp + (long)z * cBatch;
  u16* Ch = (u16*)Cp + (long)z * cBatch;
#pragma unroll
  for (int mf = 0; mf < 8; ++mf) {
#pragma unroll
    for (int nf = 0; nf < 4; ++nf) {
      const int col = colBase + nf * 16;
      const float bv = bias ? bias[col] : 0.f;
#pragma unroll
      for (int j = 0; j < 4; ++j) {
        const long row = rowBase + mf * 16 + j;
        float v = acc[mf][nf][j] + bv;
        if (flags & 1) v = fmaxf(v, 0.f);
        if (rowscale) v *= rowscale[row];
        const long idx = row * ldc + col;
        if (flags & 2) Cf[idx] = v;
        else Ch[idx] = f2bf(v);
      }
    }
  }
}

// ---------------- split-K reduce ----------------
__global__ __launch_bounds__(256) void k_splitk_reduce(
    const float* __restrict__ part, const float* __restrict__ bias,
    u16* __restrict__ dst, int total, int S) {
  int i = blockIdx.x * 256 + threadIdx.x;
  if (i >= total) return;
  float s = 0.f;
  for (int k = 0; k < S; ++k) s += part[(long)k * total + i];
  s += bias[i & 511];  // ldc = 512
  dst[i] = f2bf(fmaxf(s, 0.f));
}

// ---------------- gating: g[n] = sigmoid(lat)*sigmoid(bwd) ----------------
__global__ __launch_bounds__(256) void k_gate(
    const u16* __restrict__ lbh,
    const float* __restrict__ lw2, const float* __restrict__ lb2,
    const float* __restrict__ bw2, const float* __restrict__ bb2,
    float* __restrict__ g) {
  int w = threadIdx.x >> 6, l = threadIdx.x & 63;
  int n = blockIdx.x * 4 + w;
  const u16* rowp = lbh + (long)n * 512;
  float sa = 0.f, sb = 0.f;
#pragma unroll
  for (int j = 0; j < 4; ++j) {
    int i = l * 4 + j;
    sa += bf2f(rowp[i]) * lw2[i];
    sb += bf2f(rowp[256 + i]) * bw2[i];
  }
#pragma unroll
  for (int off = 32; off > 0; off >>= 1) {
    sa += __shfl_down(sa, off, 64);
    sb += __shfl_down(sb, off, 64);
  }
  if (l == 0) {
    float ga = 1.f / (1.f + expf(-(sa + lb2[0])));
    float gb = 1.f / (1.f + expf(-(sb + bb2[0])));
    g[n] = ga * gb;
  }
}

extern "C" void kernel_launch(void* const* d_in, const int* in_sizes, int n_in,
                              void* d_out, int out_size, void* d_ws, size_t ws_size,
                              hipStream_t stream) {
  const float* x   = (const float*)d_in[0];
  const float* ew1 = (const float*)d_in[1];
  const float* eb1 = (const float*)d_in[2];
  const float* ew2 = (const float*)d_in[3];
  const float* eb2 = (const float*)d_in[4];
  const float* dw1 = (const float*)d_in[5];
  const float* db1 = (const float*)d_in[6];
  const float* dw2 = (const float*)d_in[7];
  const float* db2 = (const float*)d_in[8];
  const float* lw1 = (const float*)d_in[9];
  const float* lb1 = (const float*)d_in[10];
  const float* lw2 = (const float*)d_in[11];
  const float* lb2 = (const float*)d_in[12];
  const float* bw1 = (const float*)d_in[13];
  const float* bb1 = (const float*)d_in[14];
  const float* bw2 = (const float*)d_in[15];
  const float* bb2 = (const float*)d_in[16];
  const float* pw1 = (const float*)d_in[17];
  const float* pb1 = (const float*)d_in[18];
  const float* pw2 = (const float*)d_in[19];
  const float* pb2 = (const float*)d_in[20];

  // split-K factor for the reduce GEMM chosen to fit ws_size (partials = S*4MB)
  int S;
  if (ws_size >= (size_t)220 * 1024 * 1024) S = 25;        // Ksplit=512,  NT=8
  else if (ws_size >= (size_t)200 * 1024 * 1024) S = 20;   // Ksplit=640,  NT=10
  else if (ws_size >= (size_t)155 * 1024 * 1024) S = 10;   // Ksplit=1280, NT=20
  else S = 2;                                              // Ksplit=6400, NT=100
  const int Ksplit = 12800 / S;

  char* p = (char*)d_ws;
  auto alloc = [&](size_t bytes) {
    char* q = p;
    p += (bytes + 255) & ~(size_t)255;
    return q;
  };
  u16* xb      = (u16*)alloc((size_t)2048 * 1024 * 2);
  u16* ew1t    = (u16*)alloc((size_t)12800 * 1024 * 2);
  u16* Wft     = (u16*)alloc((size_t)512 * 12800 * 2);
  u16* dw2t    = (u16*)alloc((size_t)256 * 512 * 2);
  u16* lbw1t   = (u16*)alloc((size_t)512 * 1024 * 2);
  u16* pw1t    = (u16*)alloc((size_t)256 * 256 * 2);
  u16* pw2t    = (u16*)alloc((size_t)256 * 256 * 2);
  float* biasf   = (float*)alloc(512 * 4);
  float* biascat = (float*)alloc(512 * 4);
  u16* dh      = (u16*)alloc((size_t)2048 * 512 * 2);
  u16* dist    = (u16*)alloc((size_t)2048 * 256 * 2);
  u16* lbh     = (u16*)alloc((size_t)2048 * 512 * 2);
  float* g     = (float*)alloc(2048 * 4);
  u16* ph      = (u16*)alloc((size_t)2048 * 256 * 2);
  float* part  = (float*)alloc((size_t)S * 2048 * 512 * 4);
  char* uni    = alloc((size_t)2048 * 12800 * 2);
  u16* h_all   = (u16*)uni;
  u16* ew2b    = (u16*)uni;
  u16* dw1t    = (u16*)(uni + (((size_t)50 * 256 * 256 * 2 + 255) & ~(size_t)255));
  (void)in_sizes; (void)n_in; (void)out_size;

  // --- precompute: bf16 conversions / transposes ---
  k_f2b<<<dim3(2048), 256, 0, stream>>>(x, xb, 2048 * 1024);
  k_f2b<<<dim3(3200), 256, 0, stream>>>(ew2, ew2b, 50 * 256 * 256);
  k_transpose_f2b<<<dim3(8, 32, 50), 256, 0, stream>>>(ew1, ew1t, 1024, 256, 1024 * 256, 256 * 1024);
  k_transpose_f2b<<<dim3(16, 400, 1), 256, 0, stream>>>(dw1, dw1t, 12800, 512, 0, 0);
  k_transpose_f2b<<<dim3(8, 16, 1), 256, 0, stream>>>(dw2, dw2t, 512, 256, 0, 0);
  k_transpose_f2b<<<dim3(8, 32, 1), 256, 0, stream>>>(lw1, lbw1t, 1024, 256, 0, 0);
  k_transpose_f2b<<<dim3(8, 32, 1), 256, 0, stream>>>(bw1, lbw1t + 256 * 1024, 1024, 256, 0, 0);
  k_transpose_f2b<<<dim3(8, 8, 1), 256, 0, stream>>>(pw1, pw1t, 256, 256, 0, 0);
  k_transpose_f2b<<<dim3(8, 8, 1), 256, 0, stream>>>(pw2, pw2t, 256, 256, 0, 0);
  k_bias_fused<<<dim3(512), 256, 0, stream>>>(dw1t, eb2, db1, biasf);
  k_concat2<<<dim3(2), 256, 0, stream>>>(lb1, bb1, biascat, 256);

  // --- Wft[e] = dw1_e^T @ ew2_e^T  (batched, M=512,N=256,K=256) ---
  k_gemm<<<dim3(2, 4, 50), 256, 0, stream>>>(
      dw1t, 12800, 256, ew2b, 256, (long)256 * 256, Wft, 12800, 256,
      256, nullptr, 0, nullptr, 0);

  // --- GEMM1 (8-phase 256^2): h_all = relu(xb @ ew1t^T + eb1) ---
  k_gemm256<<<dim3(50, 8, 1), 512, 0, stream>>>(
      xb, 1024, 0, ew1t, 1024, 0, h_all, 12800, 0,
      1024, eb1, nullptr, 1);

  // --- reduce GEMM (8-phase 256^2, split-K): part[s] = h_all[:,s] @ Wft[:,s]^T ---
  k_gemm256<<<dim3(2, 8, S), 512, 0, stream>>>(
      h_all, 12800, Ksplit, Wft, 12800, Ksplit, part, 512, (long)2048 * 512,
      Ksplit, nullptr, nullptr, 2);
  k_splitk_reduce<<<dim3(4096), 256, 0, stream>>>(part, biasf, dh, 2048 * 512, S);

  // --- dist = dh @ dw2t^T + db2 ---
  k_gemm<<<dim3(2, 16, 1), 256, 0, stream>>>(
      dh, 512, 0, dw2t, 512, 0, dist, 256, 0, 512, db2, 0, nullptr, 0);

  // --- gating hidden + gate ---
  k_gemm<<<dim3(4, 16, 1), 256, 0, stream>>>(
      xb, 1024, 0, lbw1t, 1024, 0, lbh, 512, 0, 1024, biascat, 0, nullptr, 1);
  k_gate<<<dim3(512), 256, 0, stream>>>(lbh, lw2, lb2, bw2, bb2, g);

  // --- privacy + final gated output ---
  k_gemm<<<dim3(2, 16, 1), 256, 0, stream>>>(
      dist, 256, 0, pw1t, 256, 0, ph, 256, 0, 256, pb1, 0, nullptr, 1);
  k_gemm<<<dim3(2, 16, 1), 256, 0, stream>>>(
      ph, 256, 0, pw2t, 256, 0, (float*)d_out, 256, 0, 256, pb2, 0, g, 2);
}

// Round 4
// 262.883 us; speedup vs baseline: 1.2192x; 1.2192x over previous
//
#include <hip/hip_runtime.h>
#include <hip/hip_bf16.h>

typedef unsigned short u16;
typedef __attribute__((ext_vector_type(8))) __bf16 v8bf;
typedef __attribute__((ext_vector_type(4))) float v4f;

#define DEVINL __device__ __forceinline__

DEVINL u16 f2bf(float f) {
  union { float f; unsigned u; } v; v.f = f;
  unsigned u = v.u;
  return (u16)((u + 0x7FFFu + ((u >> 16) & 1u)) >> 16);  // RNE
}
DEVINL float bf2f(u16 b) {
  union { unsigned u; float f; } v; v.u = ((unsigned)b) << 16;
  return v.f;
}

// async global->LDS, 16B per lane; dest is wave-uniform base + lane*16
DEVINL void async16(const void* g, void* l) {
  __builtin_amdgcn_global_load_lds(
      (__attribute__((address_space(1))) void*)(g),
      (__attribute__((address_space(3))) void*)(l), 16, 0, 0);
}

// ---------------- merged precompute: f2b copies + all transposes ----------------
DEVINL void f2b_body(const float* __restrict__ src, u16* __restrict__ dst, int base) {
  int i = base + threadIdx.x * 4;
  float4 v = *(const float4*)(src + i);
  unsigned lo = (unsigned)f2bf(v.x) | ((unsigned)f2bf(v.y) << 16);
  unsigned hi = (unsigned)f2bf(v.z) | ((unsigned)f2bf(v.w) << 16);
  uint2 o; o.x = lo; o.y = hi;
  *(uint2*)(dst + i) = o;
}

DEVINL void tr_body(float (*tile)[33], const float* __restrict__ src,
                    u16* __restrict__ dst, int R, int C, int bx, int by) {
  int r0 = by * 32, c0 = bx * 32;
  int tx = threadIdx.x & 31, ty = threadIdx.x >> 5;  // ty 0..7
#pragma unroll
  for (int i = 0; i < 4; ++i) {
    int rr = ty + i * 8;
    tile[rr][tx] = src[(long)(r0 + rr) * C + c0 + tx];
  }
  __syncthreads();
#pragma unroll
  for (int i = 0; i < 4; ++i) {
    int rr = ty + i * 8;
    dst[(long)(c0 + rr) * R + r0 + tx] = f2bf(tile[tx][rr]);
  }
}

__global__ __launch_bounds__(256) void k_prep(
    const float* __restrict__ x, const float* __restrict__ ew2,
    const float* __restrict__ ew1, const float* __restrict__ dw1,
    const float* __restrict__ dw2, const float* __restrict__ lw1,
    const float* __restrict__ bw1, const float* __restrict__ pw1,
    const float* __restrict__ pw2,
    u16* __restrict__ xb, u16* __restrict__ ew2b, u16* __restrict__ ew1tf,
    u16* __restrict__ dw1t, u16* __restrict__ dw2t,
    u16* __restrict__ pw1t, u16* __restrict__ pw2t) {
  __shared__ float tile[32][33];
  int b = blockIdx.x;
  if (b < 2048) { f2b_body(x, xb, b * 1024); return; }
  b -= 2048;
  if (b < 3200) { f2b_body(ew2, ew2b, b * 1024); return; }
  b -= 3200;
  if (b < 12800) {  // ew1[e]: [1024][256] -> ew1tf rows e*256..: grid (8,32) per e
    int e = b >> 8, t = b & 255;
    tr_body(tile, ew1 + (long)e * 1024 * 256, ew1tf + (long)e * 256 * 1024,
            1024, 256, t & 7, t >> 3);
    return;
  }
  b -= 12800;
  if (b < 6400) {  // dw1 [12800][512] -> dw1t [512][12800]: grid (16,400)
    tr_body(tile, dw1, dw1t, 12800, 512, b & 15, b >> 4);
    return;
  }
  b -= 6400;
  if (b < 128) {  // dw2 [512][256] -> dw2t: grid (8,16)
    tr_body(tile, dw2, dw2t, 512, 256, b & 7, b >> 3);
    return;
  }
  b -= 128;
  if (b < 256) {  // lw1 [1024][256] -> ew1tf rows 12800..: grid (8,32)
    tr_body(tile, lw1, ew1tf + (long)12800 * 1024, 1024, 256, b & 7, b >> 3);
    return;
  }
  b -= 256;
  if (b < 256) {  // bw1 -> ew1tf rows 13056..
    tr_body(tile, bw1, ew1tf + (long)13056 * 1024, 1024, 256, b & 7, b >> 3);
    return;
  }
  b -= 256;
  if (b < 64) {  // pw1 [256][256]
    tr_body(tile, pw1, pw1t, 256, 256, b & 7, b >> 3);
    return;
  }
  b -= 64;
  // pw2 [256][256]
  tr_body(tile, pw2, pw2t, 256, 256, b & 7, b >> 3);
}

// ---------------- bias concat for merged GEMM1: [eb1 | lb1 | bb1] ----------------
__global__ __launch_bounds__(256) void k_bias_build(
    const float* __restrict__ eb1, const float* __restrict__ lb1,
    const float* __restrict__ bb1, float* __restrict__ dst) {
  int i = blockIdx.x * 256 + threadIdx.x;  // 0..13311
  float v;
  if (i < 12800) v = eb1[i];
  else if (i < 13056) v = lb1[i - 12800];
  else v = bb1[i - 13056];
  dst[i] = v;
}

// ---------------- fused bias for the reduce GEMM ----------------
__global__ __launch_bounds__(256) void k_bias_fused(
    const u16* __restrict__ dw1t, const float* __restrict__ eb2,
    const float* __restrict__ db1, float* __restrict__ biasf) {
  int r = blockIdx.x;  // 0..511
  const u16* row = dw1t + (long)r * 12800;
  float s = 0.f;
  for (int i = threadIdx.x; i < 12800; i += 256) s += bf2f(row[i]) * eb2[i];
  __shared__ float red[256];
  red[threadIdx.x] = s;
  __syncthreads();
  for (int off = 128; off > 0; off >>= 1) {
    if (threadIdx.x < off) red[threadIdx.x] += red[threadIdx.x + off];
    __syncthreads();
  }
  if (threadIdx.x == 0) biasf[r] = red[0] + db1[r];
}

// ---------------- 128x128 MFMA GEMM ----------------
__global__ __launch_bounds__(256) void k_gemm(
    const u16* __restrict__ A, int lda, long aBatch,
    const u16* __restrict__ B, int ldb, long bBatch,   // B is Bt: [N][K]
    void* __restrict__ Cp, int ldc, long cBatch,
    int K,
    const float* __restrict__ bias, long biasBatch,
    const float* __restrict__ rowscale, int flags) {
  __shared__ __align__(16) u16 As[2][128 * 32];
  __shared__ __align__(16) u16 Bs[2][128 * 32];
  const int tid = threadIdx.x;
  const int w = tid >> 6, l = tid & 63;
  const int z = blockIdx.z;
  const u16* Ab = A + (long)z * aBatch + (long)blockIdx.y * 128 * lda;
  const u16* Bb = B + (long)z * bBatch + (long)blockIdx.x * 128 * ldb;
  const int ldaB = lda * 2, ldbB = ldb * 2;
  const int wm = w >> 1, wn = w & 1;
  const int r = l & 15, kq = l >> 4;

  const int f0 = w * 1024 + l * 16;
  const int f1 = f0 + 4096;
  const int row0 = f0 >> 6, cb0 = f0 & 63;
  const int row1 = f1 >> 6, cb1 = f1 & 63;
  const int seg0 = w * 1024, seg1 = seg0 + 4096;

  v4f acc[4][4];
#pragma unroll
  for (int m = 0; m < 4; ++m)
#pragma unroll
    for (int n = 0; n < 4; ++n) acc[m][n] = v4f{0.f, 0.f, 0.f, 0.f};

  const char* gA = (const char*)Ab;
  const char* gB = (const char*)Bb;
  const int nkt = K / 32;

  async16(gA + (long)row0 * ldaB + cb0, (char*)As[0] + seg0);
  async16(gA + (long)row1 * ldaB + cb1, (char*)As[0] + seg1);
  async16(gB + (long)row0 * ldbB + cb0, (char*)Bs[0] + seg0);
  async16(gB + (long)row1 * ldbB + cb1, (char*)Bs[0] + seg1);
  __syncthreads();

  for (int kt = 0; kt < nkt; ++kt) {
    const int cur = kt & 1;
    if (kt + 1 < nkt) {
      const long ko = (long)(kt + 1) * 64;
      async16(gA + ko + (long)row0 * ldaB + cb0, (char*)As[cur ^ 1] + seg0);
      async16(gA + ko + (long)row1 * ldaB + cb1, (char*)As[cur ^ 1] + seg1);
      async16(gB + ko + (long)row0 * ldbB + cb0, (char*)Bs[cur ^ 1] + seg0);
      async16(gB + ko + (long)row1 * ldbB + cb1, (char*)Bs[cur ^ 1] + seg1);
    }
    v8bf af[4], bfr[4];
#pragma unroll
    for (int m = 0; m < 4; ++m)
      af[m] = *(const v8bf*)&As[cur][(wm * 64 + m * 16 + r) * 32 + kq * 8];
#pragma unroll
    for (int n = 0; n < 4; ++n)
      bfr[n] = *(const v8bf*)&Bs[cur][(wn * 64 + n * 16 + r) * 32 + kq * 8];
#pragma unroll
    for (int m = 0; m < 4; ++m)
#pragma unroll
      for (int n = 0; n < 4; ++n)
        acc[m][n] = __builtin_amdgcn_mfma_f32_16x16x32_bf16(af[m], bfr[n], acc[m][n], 0, 0, 0);
    __syncthreads();
  }

  const float* bz = bias ? (bias + (long)z * biasBatch) : nullptr;
  const long rowBase = (long)blockIdx.y * 128 + wm * 64 + kq * 4;
  const int colBase = blockIdx.x * 128 + wn * 64 + r;
  float* Cf = (float*)Cp + (long)z * cBatch;
  u16* Ch = (u16*)Cp + (long)z * cBatch;
#pragma unroll
  for (int m = 0; m < 4; ++m) {
#pragma unroll
    for (int n = 0; n < 4; ++n) {
      const int col = colBase + n * 16;
      const float bv = bz ? bz[col] : 0.f;
#pragma unroll
      for (int i = 0; i < 4; ++i) {
        const long row = rowBase + m * 16 + i;
        float v = acc[m][n][i] + bv;
        if (flags & 1) v = fmaxf(v, 0.f);
        if (rowscale) v *= rowscale[row];
        const long idx = row * ldc + col;
        if (flags & 2) Cf[idx] = v;
        else Ch[idx] = f2bf(v);
      }
    }
  }
}

// ======================= 256x256 8-phase MFMA GEMM =======================
// BM=BN=256, BK=64, 512 threads = 8 waves (2M x 4N). XOR-swizzled LDS,
// staged via global_load_lds with pre-swizzled source. Counted vmcnt(6).
// Grid: (NX*8, 1, Z) with XCD-chunked bijective swizzle (column-major chunks).
// Requires: M%256==0, N%256==0, K%128==0, K>=256.

#define LDS_T(buf, op) (smem + ((buf) * 2 + (op)) * 16384)

#define READ_A(buf, mh) do {                                                   \
  const char* _t = (const char*)LDS_T(buf, 0);                                 \
  _Pragma("unroll") for (int m = 0; m < 4; ++m)                                \
    _Pragma("unroll") for (int kk = 0; kk < 2; ++kk)                           \
      a[m][kk] = *(const v8bf*)(_t +                                           \
        (wm * 128 + (mh) * 64 + m * 16 + r15) * 128 +                          \
        ((kk * 64 + kq * 16) ^ (swr << 4)));                                   \
} while (0)

#define READ_B(buf, nh, br) do {                                               \
  const char* _t = (const char*)LDS_T(buf, 1);                                 \
  _Pragma("unroll") for (int n = 0; n < 2; ++n)                                \
    _Pragma("unroll") for (int kk = 0; kk < 2; ++kk)                           \
      br[n][kk] = *(const v8bf*)(_t +                                          \
        (wn * 64 + (nh) * 32 + n * 16 + r15) * 128 +                          \
        ((kk * 64 + kq * 16) ^ (swr << 4)));                                   \
} while (0)

#define MMA(mh, nh, br) do {                                                   \
  _Pragma("unroll") for (int kk = 0; kk < 2; ++kk)                             \
    _Pragma("unroll") for (int m = 0; m < 4; ++m)                              \
      _Pragma("unroll") for (int n = 0; n < 2; ++n)                            \
        acc[(mh) * 4 + m][(nh) * 2 + n] =                                      \
          __builtin_amdgcn_mfma_f32_16x16x32_bf16(                             \
            a[m][kk], br[n][kk], acc[(mh) * 4 + m][(nh) * 2 + n], 0, 0, 0);    \
} while (0)

#define BAR() __builtin_amdgcn_s_barrier()
#define PRIO1() __builtin_amdgcn_s_setprio(1)
#define PRIO0() __builtin_amdgcn_s_setprio(0)
#define VM6() asm volatile("s_waitcnt vmcnt(6)" ::: "memory")
#define VM0() asm volatile("s_waitcnt vmcnt(0)" ::: "memory")

__global__ __launch_bounds__(512, 2) void k_gemm256(
    const u16* __restrict__ A, int lda, long aBatch,
    const u16* __restrict__ B, int ldb, long bBatch,   // B is Bt: [N][K]
    void* __restrict__ Cp, int ldc, long cBatch,
    int K, int NX,
    const float* __restrict__ bias,
    const float* __restrict__ rowscale, int flags) {
  __shared__ __align__(16) u16 smem[2 * 2 * 16384];  // 128 KiB

  // XCD-chunked bijective swizzle: chunk size q=NX per XCD, column-major (y fast)
  const int lin = blockIdx.x;
  const int idx = (lin & 7) * NX + (lin >> 3);
  const int by = idx & 7, bx = idx >> 3;

  const int tid = threadIdx.x;
  const int w = tid >> 6, l = tid & 63;
  const int wm = w >> 2, wn = w & 3;
  const int r15 = l & 15, kq = l >> 4, swr = l & 7;
  const int z = blockIdx.z;

  const int rl = l >> 3;
  const int scol = ((l & 7) ^ rl) << 4;

  const long ldaB = (long)lda * 2, ldbB = (long)ldb * 2;
  const char* gAs = (const char*)(A + (long)z * aBatch) +
                    ((long)by * 256 + rl) * ldaB + scol;
  const char* gBs = (const char*)(B + (long)z * bBatch) +
                    ((long)bx * 256 + rl) * ldbB + scol;

  auto stA = [&](int buf, int R0, int kt) {
    async16(gAs + (long)R0 * ldaB + (long)kt * 128, (char*)LDS_T(buf, 0) + R0 * 128);
  };
  auto stB = [&](int buf, int R0, int kt) {
    async16(gBs + (long)R0 * ldbB + (long)kt * 128, (char*)LDS_T(buf, 1) + R0 * 128);
  };
  auto stAU0 = [&](int buf, int kt) { stA(buf, w * 8, kt);       stA(buf, 128 + w * 8, kt); };
  auto stAU1 = [&](int buf, int kt) { stA(buf, 64 + w * 8, kt);  stA(buf, 192 + w * 8, kt); };
  auto stBU0 = [&](int buf, int kt) { int R = (w >> 1) * 64 + (w & 1) * 16;      stB(buf, R, kt); stB(buf, R + 8, kt); };
  auto stBU1 = [&](int buf, int kt) { int R = (w >> 1) * 64 + (w & 1) * 16 + 32; stB(buf, R, kt); stB(buf, R + 8, kt); };

  v4f acc[8][4];
#pragma unroll
  for (int m = 0; m < 8; ++m)
#pragma unroll
    for (int n = 0; n < 4; ++n) acc[m][n] = v4f{0.f, 0.f, 0.f, 0.f};
  v8bf a[4][2], b0[2][2], b1[2][2];

  const int NT = K >> 6;        // K/64 tiles; NT even, >= 4
  const int NI = (NT >> 1) - 1;

  stAU0(0, 0); stBU0(0, 0); stBU1(0, 0); stAU1(0, 0);
  stAU0(1, 1); stBU0(1, 1); stBU1(1, 1);
  VM6();
  BAR();

  int kt0 = 0;
  for (int i = 0; i < NI; ++i, kt0 += 2) {
    READ_A(0, 0); READ_B(0, 0, b0);
    stAU1(1, kt0 + 1);
    BAR(); PRIO1(); MMA(0, 0, b0); PRIO0(); BAR();
    READ_B(0, 1, b1);
    stAU0(0, kt0 + 2);
    BAR(); PRIO1(); MMA(0, 1, b1); PRIO0(); BAR();
    READ_A(0, 1);
    stBU0(0, kt0 + 2);
    BAR(); PRIO1(); MMA(1, 1, b1); PRIO0(); BAR();
    stBU1(0, kt0 + 2);
    BAR(); PRIO1(); MMA(1, 0, b0); PRIO0(); VM6(); BAR();
    READ_A(1, 0); READ_B(1, 0, b0);
    stAU1(0, kt0 + 2);
    BAR(); PRIO1(); MMA(0, 0, b0); PRIO0(); BAR();
    READ_B(1, 1, b1);
    stAU0(1, kt0 + 3);
    BAR(); PRIO1(); MMA(0, 1, b1); PRIO0(); BAR();
    READ_A(1, 1);
    stBU0(1, kt0 + 3);
    BAR(); PRIO1(); MMA(1, 1, b1); PRIO0(); BAR();
    stBU1(1, kt0 + 3);
    BAR(); PRIO1(); MMA(1, 0, b0); PRIO0(); VM6(); BAR();
  }

  READ_A(0, 0); READ_B(0, 0, b0);
  stAU1(1, kt0 + 1);
  BAR(); PRIO1(); MMA(0, 0, b0); PRIO0(); BAR();
  READ_B(0, 1, b1);
  BAR(); PRIO1(); MMA(0, 1, b1); PRIO0(); BAR();
  READ_A(0, 1);
  BAR(); PRIO1(); MMA(1, 1, b1); PRIO0(); BAR();
  BAR(); PRIO1(); MMA(1, 0, b0); PRIO0(); VM0(); BAR();
  READ_A(1, 0); READ_B(1, 0, b0);
  BAR(); PRIO1(); MMA(0, 0, b0); PRIO0(); BAR();
  READ_B(1, 1, b1);
  BAR(); PRIO1(); MMA(0, 1, b1); PRIO0(); BAR();
  READ_A(1, 1);
  BAR(); PRIO1(); MMA(1, 1, b1); PRIO0(); BAR();
  PRIO1(); MMA(1, 0, b0); PRIO0();

  const long rowBase = (long)by * 256 + wm * 128 + kq * 4;
  const int colBase = bx * 256 + wn * 64 + r15;
  float* Cf = (float*)Cp + (long)z * cBatch;
  u16* Ch = (u16*)Cp + (long)z * cBatch;
#pragma unroll
  for (int mf = 0; mf < 8; ++mf) {
#pragma unroll
    for (int nf = 0; nf < 4; ++nf) {
      const int col = colBase + nf * 16;
      const float bv = bias ? bias[col] : 0.f;
#pragma unroll
      for (int j = 0; j < 4; ++j) {
        const long row = rowBase + mf * 16 + j;
        float v = acc[mf][nf][j] + bv;
        if (flags & 1) v = fmaxf(v, 0.f);
        if (rowscale) v *= rowscale[row];
        const long idx = row * ldc + col;
        if (flags & 2) Cf[idx] = v;
        else Ch[idx] = f2bf(v);
      }
    }
  }
}

// ---------------- split-K reduce ----------------
__global__ __launch_bounds__(256) void k_splitk_reduce(
    const float* __restrict__ part, const float* __restrict__ bias,
    u16* __restrict__ dst, int total, int S) {
  int i = blockIdx.x * 256 + threadIdx.x;
  if (i >= total) return;
  float s = 0.f;
  for (int k = 0; k < S; ++k) s += part[(long)k * total + i];
  s += bias[i & 511];  // ldc = 512
  dst[i] = f2bf(fmaxf(s, 0.f));
}

// ---------------- gating: g[n] = sigmoid(lat)*sigmoid(bwd) ----------------
__global__ __launch_bounds__(256) void k_gate(
    const u16* __restrict__ lbh, int lda,
    const float* __restrict__ lw2, const float* __restrict__ lb2,
    const float* __restrict__ bw2, const float* __restrict__ bb2,
    float* __restrict__ g) {
  int w = threadIdx.x >> 6, l = threadIdx.x & 63;
  int n = blockIdx.x * 4 + w;
  const u16* rowp = lbh + (long)n * lda;
  float sa = 0.f, sb = 0.f;
#pragma unroll
  for (int j = 0; j < 4; ++j) {
    int i = l * 4 + j;
    sa += bf2f(rowp[i]) * lw2[i];
    sb += bf2f(rowp[256 + i]) * bw2[i];
  }
#pragma unroll
  for (int off = 32; off > 0; off >>= 1) {
    sa += __shfl_down(sa, off, 64);
    sb += __shfl_down(sb, off, 64);
  }
  if (l == 0) {
    float ga = 1.f / (1.f + expf(-(sa + lb2[0])));
    float gb = 1.f / (1.f + expf(-(sb + bb2[0])));
    g[n] = ga * gb;
  }
}

extern "C" void kernel_launch(void* const* d_in, const int* in_sizes, int n_in,
                              void* d_out, int out_size, void* d_ws, size_t ws_size,
                              hipStream_t stream) {
  const float* x   = (const float*)d_in[0];
  const float* ew1 = (const float*)d_in[1];
  const float* eb1 = (const float*)d_in[2];
  const float* ew2 = (const float*)d_in[3];
  const float* eb2 = (const float*)d_in[4];
  const float* dw1 = (const float*)d_in[5];
  const float* db1 = (const float*)d_in[6];
  const float* dw2 = (const float*)d_in[7];
  const float* db2 = (const float*)d_in[8];
  const float* lw1 = (const float*)d_in[9];
  const float* lb1 = (const float*)d_in[10];
  const float* lw2 = (const float*)d_in[11];
  const float* lb2 = (const float*)d_in[12];
  const float* bw1 = (const float*)d_in[13];
  const float* bb1 = (const float*)d_in[14];
  const float* bw2 = (const float*)d_in[15];
  const float* bb2 = (const float*)d_in[16];
  const float* pw1 = (const float*)d_in[17];
  const float* pb1 = (const float*)d_in[18];
  const float* pw2 = (const float*)d_in[19];
  const float* pb2 = (const float*)d_in[20];

  const int S = 4, Ksplit = 3200;  // reduce GEMM split-K: 256 blocks, 16 MB partials

  char* p = (char*)d_ws;
  auto alloc = [&](size_t bytes) {
    char* q = p;
    p += (bytes + 255) & ~(size_t)255;
    return q;
  };
  u16* xb      = (u16*)alloc((size_t)2048 * 1024 * 2);
  u16* ew1tf   = (u16*)alloc((size_t)13312 * 1024 * 2);  // [ew1t | lw1t | bw1t]
  u16* Wft     = (u16*)alloc((size_t)512 * 12800 * 2);
  u16* dw2t    = (u16*)alloc((size_t)256 * 512 * 2);
  u16* pw1t    = (u16*)alloc((size_t)256 * 256 * 2);
  u16* pw2t    = (u16*)alloc((size_t)256 * 256 * 2);
  float* ebcat = (float*)alloc(13312 * 4);
  float* biasf = (float*)alloc(512 * 4);
  u16* dh      = (u16*)alloc((size_t)2048 * 512 * 2);
  u16* dist    = (u16*)alloc((size_t)2048 * 256 * 2);
  float* g     = (float*)alloc(2048 * 4);
  u16* ph      = (u16*)alloc((size_t)2048 * 256 * 2);
  float* part  = (float*)alloc((size_t)S * 2048 * 512 * 4);
  char* uni    = alloc((size_t)2048 * 13312 * 2);  // h_all; pre-GEMM1 aliases ew2b+dw1t
  u16* h_all   = (u16*)uni;
  u16* ew2b    = (u16*)uni;
  u16* dw1t    = (u16*)(uni + (((size_t)50 * 256 * 256 * 2 + 255) & ~(size_t)255));
  (void)in_sizes; (void)n_in; (void)out_size; (void)ws_size;

  // --- merged precompute (1 launch): f2b x, f2b ew2, 7 transposes ---
  k_prep<<<dim3(25216), 256, 0, stream>>>(
      x, ew2, ew1, dw1, dw2, lw1, bw1, pw1, pw2,
      xb, ew2b, ew1tf, dw1t, dw2t, pw1t, pw2t);
  k_bias_build<<<dim3(52), 256, 0, stream>>>(eb1, lb1, bb1, ebcat);
  k_bias_fused<<<dim3(512), 256, 0, stream>>>(dw1t, eb2, db1, biasf);

  // --- Wft[e] = dw1_e^T @ ew2_e^T  (batched, M=512,N=256,K=256) ---
  k_gemm<<<dim3(2, 4, 50), 256, 0, stream>>>(
      dw1t, 12800, 256, ew2b, 256, (long)256 * 256, Wft, 12800, 256,
      256, nullptr, 0, nullptr, 0);

  // --- GEMM1 (8-phase 256^2, lbh merged): h_all = relu(xb @ [ew1|lw1|bw1]^T + ebcat)
  //     M=2048, N=13312, K=1024; grid NX=52 x NY=8 = 416 blocks, XCD-swizzled ---
  k_gemm256<<<dim3(416, 1, 1), 512, 0, stream>>>(
      xb, 1024, 0, ew1tf, 1024, 0, h_all, 13312, 0,
      1024, 52, ebcat, nullptr, 1);

  // --- gating scalars from merged columns 12800..13311 ---
  k_gate<<<dim3(512), 256, 0, stream>>>(h_all + 12800, 13312, lw2, lb2, bw2, bb2, g);

  // --- reduce GEMM (128^2, split-K S=4, 256 blocks = 1/CU): part[z] = h_all[:,z] @ Wft[:,z]^T ---
  k_gemm<<<dim3(4, 16, S), 256, 0, stream>>>(
      h_all, 13312, Ksplit, Wft, 12800, Ksplit, part, 512, (long)2048 * 512,
      Ksplit, nullptr, 0, nullptr, 2);
  k_splitk_reduce<<<dim3(4096), 256, 0, stream>>>(part, biasf, dh, 2048 * 512, S);

  // --- dist = dh @ dw2t^T + db2 ---
  k_gemm<<<dim3(2, 16, 1), 256, 0, stream>>>(
      dh, 512, 0, dw2t, 512, 0, dist, 256, 0, 512, db2, 0, nullptr, 0);

  // --- privacy + final gated output ---
  k_gemm<<<dim3(2, 16, 1), 256, 0, stream>>>(
      dist, 256, 0, pw1t, 256, 0, ph, 256, 0, 256, pb1, 0, nullptr, 1);
  k_gemm<<<dim3(2, 16, 1), 256, 0, stream>>>(
      ph, 256, 0, pw2t, 256, 0, (float*)d_out, 256, 0, 256, pb2, 0, g, 2);
}